// Round 15
// baseline (148.924 us; speedup 1.0000x reference)
//
#include <hip/hip_runtime.h>
#include <math.h>

// Problem constants
#define KS    11
#define H     512
#define W     512
#define OH    502
#define OW    502
#define NPLANES 48
#define TOTAL_OUT (NPLANES * OH * OW)   // 12,096,192

// Round 15: r13 full-width structure + DOUBLE-BUFFERED LDS, ONE barrier/iter.
// stage2(it) reads buf[cur] while stage1(it+1) writes buf[cur^1] -> no hazard between
// the same barrier pair -> compiler interleaves both FMA streams (within-wave ILP;
// r14 showed idle is cross-iteration dependency stall, not barrier skew).
#define TH      4
#define IROWS   (TH + KS - 1)     // 14 input rows in the register window
#define LVWP    523               // row stride in float2 (1046 words == 22 mod 32; 0 conflicts measured r13)
#define NTHREADS 512
#define CHUNK   48                // 11 chunks: 10x48 + 22; 528 blocks ~= 2/CU (LDS-bound)
#define NCHUNKS 11

typedef float v2f __attribute__((ext_vector_type(2)));

__global__ void zero_out_kernel(float* out) { out[0] = 0.0f; }

__device__ __forceinline__ float uniform_f(float v) {
    // v is wave-uniform; route through readfirstlane to place it in an SGPR.
    return __int_as_float(__builtin_amdgcn_readfirstlane(__float_as_int(v)));
}

// EMPIRICAL launch_bounds 2nd-arg law (r1/r2/r7): VGPR cap ~= 256/arg.
// arg=3 -> cap 84 >= live set ~80 (ring 28 + nt 8 + A/B 16 + M 16 + addr).
// At <=84 VGPR: 4 waves/SIMD; LDS 67 KB -> 2 blocks/CU -> 16 waves/CU.
__global__ __launch_bounds__(NTHREADS, 3) void ssim_kernel(
    const float* __restrict__ x,
    const float* __restrict__ y,
    const float* __restrict__ win,
    float* __restrict__ out)
{
    __shared__ v2f vp[2][2][TH][LVWP];   // [buf][pair][row][col] = 66,944 B
    __shared__ float w1s[KS];
    __shared__ float wsum[NTHREADS / 64];

    const int t     = threadIdx.x;          // == input column
    const int chunk = blockIdx.x;           // 0..10
    const int plane = blockIdx.y;           // 0..47

    const int row_lo = chunk * CHUNK;
    const int row_hi = (row_lo + CHUNK < OH) ? (row_lo + CHUNK) : OH;
    const int niter  = (row_hi - row_lo + TH - 1) / TH;   // 12 (chunks 0-9), 6 (chunk 10)

    const float* __restrict__ xp = x + (size_t)plane * (H * W);
    const float* __restrict__ yp = y + (size_t)plane * (H * W);

    // Separable taps: window = outer(g,g) => g[i] = sqrt(win[i][i])
    if (t < KS) w1s[t] = sqrtf(win[t * KS + t]);
    __syncthreads();

    // Taps wave-uniform -> SGPRs (measured r6: saves 11+ VGPRs).
    float w[KS];
#pragma unroll
    for (int k = 0; k < KS; k++) w[k] = uniform_f(w1s[k]);

    // Stage-2 mapping (measured 0-conflict in r13, same bank class): 4 rows x 128 runs.
    const int r  = t & 3;
    const int c0 = (t >> 2) << 2;            // 0..508; reads elements c0..c0+13 <= 521 < 523
    const float c1 = 1e-4f;   // (0.01)^2
    const float c2 = 9e-4f;   // (0.03)^2
    float acc = 0.f;

    // ---- Prime the register ring: rows row_lo..row_lo+13 (max 493, in range) ----
    float rx[IROWS], ry[IROWS];
#pragma unroll
    for (int j = 0; j < IROWS; j++) {
        const int gy = row_lo + j;
        rx[j] = xp[gy * W + t];
        ry[j] = yp[gy * W + t];
    }

    // ---- Prologue: stage1(it=0) -> buf 0 ----
    {
        v2f A[TH], B[TH];
#pragma unroll
        for (int q = 0; q < TH; q++) { A[q] = (v2f){0.f, 0.f}; B[q] = (v2f){0.f, 0.f}; }
#pragma unroll
        for (int j = 0; j < IROWS; j++) {
            const float xv = rx[j], yv = ry[j];
            const v2f d0 = {xv, yv};
            const v2f d1 = {xv * xv + yv * yv, xv * yv};
#pragma unroll
            for (int q = 0; q < TH; q++) {
                if (j - q >= 0 && j - q < KS) {
                    const float wk = w[j - q];
                    A[q] += wk * d0;
                    B[q] += wk * d1;
                }
            }
        }
#pragma unroll
        for (int q = 0; q < TH; q++) { vp[0][0][q][t] = A[q]; vp[0][1][q][t] = B[q]; }
    }
    __syncthreads();    // buf0 ready

    int cur = 0;
    for (int it = 0; it < niter; ++it) {
        const int gy0 = row_lo + it * TH;
        const bool more = (it + 1 < niter);   // uniform across block

        // ---- Prefetch rows for stage1(it+1): issued first, consumed ~600 cyc later ----
        float ntx[TH], nty[TH];
        if (more) {
#pragma unroll
            for (int j = 0; j < TH; j++) {
                int gy = gy0 + IROWS + j;            // rows gy0+14..gy0+17
                gy = (gy < H - 1) ? gy : (H - 1);    // clamp feeds only discarded rows
                ntx[j] = xp[gy * W + t];
                nty[j] = yp[gy * W + t];
            }
        }

        // ---- Stage 2 (reads vp[cur]) : hconv streaming + interleavable with stage1 below ----
        v2f M0[TH], M1[TH];
#pragma unroll
        for (int p = 0; p < TH; p++) { M0[p] = (v2f){0.f, 0.f}; M1[p] = (v2f){0.f, 0.f}; }
#pragma unroll
        for (int k = 0; k < IROWS; k++) {
            const v2f p0 = vp[cur][0][r][c0 + k];    // aligned ds_read_b64, 0-conflict class
            const v2f p1 = vp[cur][1][r][c0 + k];
#pragma unroll
            for (int p = 0; p < TH; p++) {
                if (k - p >= 0 && k - p < KS) {
                    const float wk = w[k - p];
                    M0[p] += wk * p0;
                    M1[p] += wk * p1;
                }
            }
        }

        // ---- Stage 1 for it+1 (writes vp[cur^1]) — independent of stage 2 above ----
        if (more) {
#pragma unroll
            for (int j = 0; j < IROWS - TH; j++) { rx[j] = rx[j + TH]; ry[j] = ry[j + TH]; }
#pragma unroll
            for (int j = 0; j < TH; j++) { rx[IROWS - TH + j] = ntx[j]; ry[IROWS - TH + j] = nty[j]; }

            v2f A[TH], B[TH];
#pragma unroll
            for (int q = 0; q < TH; q++) { A[q] = (v2f){0.f, 0.f}; B[q] = (v2f){0.f, 0.f}; }
#pragma unroll
            for (int j = 0; j < IROWS; j++) {
                const float xv = rx[j], yv = ry[j];
                const v2f d0 = {xv, yv};
                const v2f d1 = {xv * xv + yv * yv, xv * yv};
#pragma unroll
                for (int q = 0; q < TH; q++) {
                    if (j - q >= 0 && j - q < KS) {
                        const float wk = w[j - q];
                        A[q] += wk * d0;
                        B[q] += wk * d1;
                    }
                }
            }
#pragma unroll
            for (int q = 0; q < TH; q++) { vp[cur ^ 1][0][q][t] = A[q]; vp[cur ^ 1][1][q][t] = B[q]; }
        }

        // ---- SSIM epilogue for this iteration (uses M, independent of stage1) ----
        const int grow  = gy0 + r;
        const bool rowok = (grow < row_hi);
#pragma unroll
        for (int p = 0; p < TH; p++) {
            if (rowok && (c0 + p) < OW) {
                const float mux = M0[p][0], muy = M0[p][1];
                const float mxy = mux * muy;
                const float m2  = mux * mux + muy * muy;
                const float sss = M1[p][0] - m2;        // sigma_x^2 + sigma_y^2
                const float sxy = M1[p][1] - mxy;
                const float num = (2.f * sxy + c2) * (2.f * mxy + c1);
                const float den = (sss + c2) * (m2 + c1);
                acc += num * __builtin_amdgcn_rcpf(den);
            }
        }

        if (more) __syncthreads();   // ONE barrier/iter: vp[cur^1] ready for next stage2
        cur ^= 1;
    }

    // ---- Reduction: wave shuffle -> cross-wave LDS -> one atomic/block ----
#pragma unroll
    for (int off = 32; off > 0; off >>= 1)
        acc += __shfl_down(acc, off, 64);

    if ((t & 63) == 0) wsum[t >> 6] = acc;
    __syncthreads();
    if (t == 0) {
        float s = 0.f;
#pragma unroll
        for (int i = 0; i < NTHREADS / 64; i++) s += wsum[i];
        atomicAdd(out, s * (1.0f / (float)TOTAL_OUT));
    }
}

extern "C" void kernel_launch(void* const* d_in, const int* in_sizes, int n_in,
                              void* d_out, int out_size, void* d_ws, size_t ws_size,
                              hipStream_t stream)
{
    const float* x   = (const float*)d_in[0];
    const float* y   = (const float*)d_in[1];
    const float* win = (const float*)d_in[2];
    float* out = (float*)d_out;

    zero_out_kernel<<<1, 1, 0, stream>>>(out);

    // (11 chunks, 48 planes) = 528 blocks ~= 2/CU (LDS-bound); the short last chunk
    // (22 rows) plus the 16-block overflow form a small tail.
    dim3 grid(NCHUNKS, NPLANES);
    ssim_kernel<<<grid, NTHREADS, 0, stream>>>(x, y, win, out);
}

// Round 16
// 138.872 us; speedup vs baseline: 1.0724x; 1.0724x over previous
//
#include <hip/hip_runtime.h>
#include <math.h>

// Problem constants
#define KS    11
#define H     512
#define W     512
#define OH    502
#define OW    502
#define NPLANES 48
#define TOTAL_OUT (NPLANES * OH * OW)   // 12,096,192

// Round 16: r13 structure + FUSED float4 LDS element {mu_x, mu_y, pss, pxy}.
// DS instrs per thread-iter: 36 b64 -> 18 b128 (4 write + 14 read), same bytes.
// b128 is always 16B-aligned (float4 elements); LVW4 == 1 mod 8 makes every
// b128 access exactly 8 dwords/bank = the bank-minimum (r13's b64 reads were 4-way).
#define TH      4
#define IROWS   (TH + KS - 1)     // 14 input rows in the register window
#define LVW4    529               // row stride in float4 elements; 529 % 8 == 1 (bank-optimal)
#define NTHREADS 512
#define CHUNK   24                // 21 chunks x 24 = 504 >= 502
#define NCHUNKS 21

typedef float v2f __attribute__((ext_vector_type(2)));
typedef float v4f __attribute__((ext_vector_type(4)));

__global__ void zero_out_kernel(float* out) { out[0] = 0.0f; }

__device__ __forceinline__ float uniform_f(float v) {
    // v is wave-uniform; route through readfirstlane to place it in an SGPR.
    return __int_as_float(__builtin_amdgcn_readfirstlane(__float_as_int(v)));
}

// EMPIRICAL launch_bounds 2nd-arg law (r1/r2/r7): VGPR cap ~= 256/arg. arg=4 -> cap 64
// >= r13's measured 48 -> no spill; <=64 regs keeps 8 waves/SIMD.
// LDS 4 x 529 x 16B = 33,856 B -> 4 blocks x 8 waves = 32 waves/CU.
__global__ __launch_bounds__(NTHREADS, 4) void ssim_kernel(
    const float* __restrict__ x,
    const float* __restrict__ y,
    const float* __restrict__ win,
    float* __restrict__ out)
{
    __shared__ v4f vp[TH][LVW4];         // 33,856 B -> 4 blocks/CU
    __shared__ float w1s[KS];
    __shared__ float wsum[NTHREADS / 64];

    const int t     = threadIdx.x;          // == input column
    const int chunk = blockIdx.x;           // 0..20
    const int plane = blockIdx.y;           // 0..47

    const int row_lo = chunk * CHUNK;
    const int row_hi = (row_lo + CHUNK < OH) ? (row_lo + CHUNK) : OH;
    const int niter  = (row_hi - row_lo + TH - 1) / TH;   // 6 for all chunks (runtime -> rolled)

    const float* __restrict__ xp = x + (size_t)plane * (H * W);
    const float* __restrict__ yp = y + (size_t)plane * (H * W);

    // Separable taps: window = outer(g,g) => g[i] = sqrt(win[i][i])
    if (t < KS) w1s[t] = sqrtf(win[t * KS + t]);
    __syncthreads();

    // Taps wave-uniform -> SGPRs (measured r6: saves 11+ VGPRs).
    float w[KS];
#pragma unroll
    for (int k = 0; k < KS; k++) w[k] = uniform_f(w1s[k]);

    // Stage-2 mapping: 4 rows x 128 runs of 4 px.
    // b128 element residue (r + 4(u&1) + k) mod 8 -> uniform 8 lanes/class ->
    // 8 dwords/bank per access = bank minimum.
    const int r  = t & 3;
    const int c0 = (t >> 2) << 2;            // 0..508; reads elements c0..c0+13 <= 521 < 529
    const float c1 = 1e-4f;   // (0.01)^2
    const float c2 = 9e-4f;   // (0.03)^2
    float acc = 0.f;

    // ---- Prime the register ring: rows row_lo..row_lo+13 (max 493, in range) ----
    float rx[IROWS], ry[IROWS];
#pragma unroll
    for (int j = 0; j < IROWS; j++) {
        const int gy = row_lo + j;
        rx[j] = xp[gy * W + t];
        ry[j] = yp[gy * W + t];
    }

    for (int it = 0; it < niter; ++it) {
        const int gy0 = row_lo + it * TH;

        // ---- Stage 1: vertical 11-tap conv, packed: A={mu_x,mu_y}, B={pss,pxy} ----
        v2f A[TH], B[TH];
#pragma unroll
        for (int q = 0; q < TH; q++) { A[q] = (v2f){0.f, 0.f}; B[q] = (v2f){0.f, 0.f}; }

#pragma unroll
        for (int j = 0; j < IROWS; j++) {
            const float xv = rx[j], yv = ry[j];
            const v2f d0 = {xv, yv};
            const v2f d1 = {xv * xv + yv * yv, xv * yv};
#pragma unroll
            for (int q = 0; q < TH; q++) {
                if (j - q >= 0 && j - q < KS) {    // constant-folds after unroll
                    const float wk = w[j - q];
                    A[q] += wk * d0;               // v_pk_fma_f32
                    B[q] += wk * d1;               // v_pk_fma_f32
                }
            }
        }

        __syncthreads();    // barrier 1: previous iteration's stage-2 reads of vp are done
#pragma unroll
        for (int q = 0; q < TH; q++) {      // ONE ds_write_b128 per row: {A, B} fused
            v4f o;
            o.x = A[q].x; o.y = A[q].y; o.z = B[q].x; o.w = B[q].y;
            vp[q][t] = o;
        }
        __syncthreads();    // barrier 2: vp ready

        // ---- Slide the ring + prefetch 4 new rows per image (8 loads) ----
        // First use is NEXT iteration's vconv; no barrier between issue and use,
        // so the vmcnt(0)-before-s_barrier drain never exposes these loads.
        if (it + 1 < niter) {
#pragma unroll
            for (int j = 0; j < IROWS - TH; j++) {
                rx[j] = rx[j + TH];
                ry[j] = ry[j + TH];
            }
#pragma unroll
            for (int j = 0; j < TH; j++) {
                int gy = gy0 + IROWS + j;            // rows gy0+14..gy0+17
                gy = (gy < H - 1) ? gy : (H - 1);    // clamp feeds only discarded rows
                rx[IROWS - TH + j] = xp[gy * W + t];
                ry[IROWS - TH + j] = yp[gy * W + t];
            }
        }

        // ---- Stage 2: horizontal 11-tap conv, streaming: ONE b128 read per tap-col ----
        v2f M0[TH], M1[TH];
#pragma unroll
        for (int p = 0; p < TH; p++) { M0[p] = (v2f){0.f, 0.f}; M1[p] = (v2f){0.f, 0.f}; }

#pragma unroll
        for (int k = 0; k < IROWS; k++) {
            const v4f f = vp[r][c0 + k];         // aligned ds_read_b128, bank-minimal
            const v2f p0 = f.xy;                 // {mu_x, mu_y}
            const v2f p1 = f.zw;                 // {pss,  pxy }
#pragma unroll
            for (int p = 0; p < TH; p++) {
                if (k - p >= 0 && k - p < KS) {   // constant-folds after unroll
                    const float wk = w[k - p];
                    M0[p] += wk * p0;             // v_pk_fma_f32
                    M1[p] += wk * p1;             // v_pk_fma_f32
                }
            }
        }

        const int grow  = gy0 + r;
        const bool rowok = (grow < row_hi);
#pragma unroll
        for (int p = 0; p < TH; p++) {
            if (rowok && (c0 + p) < OW) {
                const float mux = M0[p][0], muy = M0[p][1];
                const float mxy = mux * muy;
                const float m2  = mux * mux + muy * muy;
                const float sss = M1[p][0] - m2;        // sigma_x^2 + sigma_y^2
                const float sxy = M1[p][1] - mxy;
                const float num = (2.f * sxy + c2) * (2.f * mxy + c1);
                const float den = (sss + c2) * (m2 + c1);
                acc += num * __builtin_amdgcn_rcpf(den);
            }
        }
    }

    // ---- Reduction: wave shuffle -> cross-wave LDS -> one atomic/block ----
#pragma unroll
    for (int off = 32; off > 0; off >>= 1)
        acc += __shfl_down(acc, off, 64);

    if ((t & 63) == 0) wsum[t >> 6] = acc;
    __syncthreads();
    if (t == 0) {
        float s = 0.f;
#pragma unroll
        for (int i = 0; i < NTHREADS / 64; i++) s += wsum[i];
        atomicAdd(out, s * (1.0f / (float)TOTAL_OUT));
    }
}

extern "C" void kernel_launch(void* const* d_in, const int* in_sizes, int n_in,
                              void* d_out, int out_size, void* d_ws, size_t ws_size,
                              hipStream_t stream)
{
    const float* x   = (const float*)d_in[0];
    const float* y   = (const float*)d_in[1];
    const float* win = (const float*)d_in[2];
    float* out = (float*)d_out;

    zero_out_kernel<<<1, 1, 0, stream>>>(out);

    // (21 chunks, 48 planes) = 1008 blocks ~= 4/CU x 256 CUs, single round
    // -> 4 independent 8-wave barrier domains per CU, 32 waves/CU.
    dim3 grid(NCHUNKS, NPLANES);
    ssim_kernel<<<grid, NTHREADS, 0, stream>>>(x, y, win, out);
}